// Round 4
// baseline (232.435 us; speedup 1.0000x reference)
//
#include <hip/hip_runtime.h>

typedef __attribute__((ext_vector_type(8))) short short8;
typedef __attribute__((ext_vector_type(4))) float floatx4;

__device__ __forceinline__ unsigned short f2bf(float f) {
    union { float f; unsigned int u; } v; v.f = f;
    unsigned int r = (v.u + 0x7fffu + ((v.u >> 16) & 1u)) >> 16;
    return (unsigned short)r;
}

// ---------------------------------------------------------------------------
// W-prep: w1 -> [c4=4][tap=9][co=64][ci=32] bf16 ; w2 -> [c4=2][tap=9][co=32][ci=32]
// ---------------------------------------------------------------------------
__global__ __launch_bounds__(256) void prep_w_kernel(
    const float* __restrict__ w1, const float* __restrict__ w2,
    unsigned short* __restrict__ w1p, unsigned short* __restrict__ w2p)
{
    int i = blockIdx.x * 256 + threadIdx.x;
    if (i < 4 * 9 * 64 * 32) {
        int ci = i & 31; int t2 = i >> 5; int co = t2 & 63; int t3 = t2 >> 6;
        int tap = t3 % 9; int c4 = t3 / 9;
        float v = 0.f;
        if (co < 50) v = w1[((size_t)co * 128 + c4 * 32 + ci) * 9 + tap];
        w1p[i] = f2bf(v);
    } else {
        int j = i - 4 * 9 * 64 * 32;
        int ci = j & 31; int t2 = j >> 5; int co = t2 & 31; int t3 = t2 >> 5;
        int tap = t3 % 9; int c4 = t3 / 9;
        int cig = c4 * 32 + ci;
        float v = 0.f;
        if (co < 18 && cig < 50) v = w2[((size_t)co * 50 + cig) * 9 + tap];
        w2p[j] = f2bf(v);
    }
}

// ---------------------------------------------------------------------------
// conv1 MFMA (fused NCHW->NHWC transpose in staging):
// ctrl [8,128ci,128y,128x] f32 -> h NHWC bf16 [8,128,128,64]; bias+ReLU+BN.
// M-tile 256 px (16x16), N = 64 co. Wave: 4 mt x 4 nt. grid (8,8,8).
// Staging: per (ci,y) row load 6 aligned float4 covering [x0-4, x0+20);
// x0 % 16 == 0 so windows are always fully-valid or fully-OOB (zero).
// ---------------------------------------------------------------------------
__global__ __launch_bounds__(256) void conv1_mfma(
    const float* __restrict__ ctrl, const unsigned short* __restrict__ w1p,
    const float* __restrict__ b1, const float* __restrict__ gamma,
    const float* __restrict__ beta, const float* __restrict__ mean,
    const float* __restrict__ var, unsigned short* __restrict__ h)
{
    __shared__ unsigned short in_s[324 * 40];     // 18x18 px halo, 32 ci (pad 40)
    __shared__ unsigned short w_s[9 * 64 * 40];   // tap x co x 32 ci
    const int tid = threadIdx.x;
    const int x0 = blockIdx.x * 16, y0 = blockIdx.y * 16, b = blockIdx.z;
    const int wid = tid >> 6, lane = tid & 63;
    const int ln = lane & 15, q = lane >> 4;

    floatx4 acc[4][4];
#pragma unroll
    for (int mt = 0; mt < 4; mt++)
#pragma unroll
        for (int nt = 0; nt < 4; nt++) acc[mt][nt] = (floatx4)(0.f);

    for (int c4 = 0; c4 < 4; c4++) {
        // stage input: 32 ci x 18 y x 6 float4 windows = 3456
        for (int i = tid; i < 3456; i += 256) {
            int xg = i % 6;
            int ci = (i / 6) % 32;
            int y  = i / 192;                       // 0..17
            int gy = y0 + y - 1;
            int gx0 = x0 - 4 + xg * 4;
            float4 v = make_float4(0.f, 0.f, 0.f, 0.f);
            if (gy >= 0 && gy < 128 && gx0 >= 0 && gx0 + 3 < 128)
                v = *(const float4*)&ctrl[(((size_t)b * 128 + c4 * 32 + ci) * 128 + gy) * 128 + gx0];
            const float* vf = (const float*)&v;
#pragma unroll
            for (int k = 0; k < 4; k++) {
                int xl = xg * 4 + k - 3;            // px x index in [-3, 20]
                if (xl >= 0 && xl < 18)
                    in_s[(y * 18 + xl) * 40 + ci] = f2bf(vf[k]);
            }
        }
        // stage weights: 2304 uint4
#pragma unroll
        for (int it = 0; it < 9; it++) {
            int f = it * 256 + tid;
            int g = f & 3, co = (f >> 2) & 63, tap = f >> 8;
            uint4 v = *(const uint4*)&w1p[(((size_t)c4 * 9 + tap) * 64 + co) * 32 + g * 8];
            *(uint4*)&w_s[(tap * 64 + co) * 40 + g * 8] = v;
        }
        __syncthreads();

#pragma unroll
        for (int tap = 0; tap < 9; tap++) {
            const int dy = tap / 3, dx = tap % 3;
            short8 a[4];
#pragma unroll
            for (int mt = 0; mt < 4; mt++)
                a[mt] = *(const short8*)&in_s[((wid * 4 + mt + dy) * 18 + ln + dx) * 40 + q * 8];
#pragma unroll
            for (int nt = 0; nt < 4; nt++) {
                short8 bf = *(const short8*)&w_s[(tap * 64 + nt * 16 + ln) * 40 + q * 8];
#pragma unroll
                for (int mt = 0; mt < 4; mt++)
                    acc[mt][nt] = __builtin_amdgcn_mfma_f32_16x16x32_bf16(a[mt], bf, acc[mt][nt], 0, 0, 0);
            }
        }
        __syncthreads();
    }

#pragma unroll
    for (int nt = 0; nt < 4; nt++) {
        int co = nt * 16 + ln;
        bool real = co < 50;
        float sc = 0.f, mn = 0.f, bt = 0.f, bs = 0.f;
        if (real) {
            sc = gamma[co] * rsqrtf(var[co] + 1e-5f);
            mn = mean[co]; bt = beta[co]; bs = b1[co];
        }
#pragma unroll
        for (int mt = 0; mt < 4; mt++) {
            int gy = y0 + wid * 4 + mt;
#pragma unroll
            for (int r = 0; r < 4; r++) {
                int px = q * 4 + r;
                float v = 0.f;
                if (real) {
                    float tv = fmaxf(acc[mt][nt][r] + bs, 0.f);
                    v = (tv - mn) * sc + bt;
                }
                h[(((size_t)b * 128 + gy) * 128 + x0 + px) * 64 + co] = f2bf(v);
            }
        }
    }
}

// ---------------------------------------------------------------------------
// conv2 MFMA: M-tile 256 px, N = 32 (18 real). Wave: 4 mt x 2 nt. grid (8,8,8)
// ---------------------------------------------------------------------------
__global__ __launch_bounds__(256) void conv2_mfma(
    const unsigned short* __restrict__ hT, const unsigned short* __restrict__ w2p,
    const float* __restrict__ b2, float* __restrict__ cond)
{
    __shared__ unsigned short in_s[324 * 40];
    __shared__ unsigned short w_s[9 * 32 * 40];
    const int tid = threadIdx.x;
    const int x0 = blockIdx.x * 16, y0 = blockIdx.y * 16, b = blockIdx.z;
    const int wid = tid >> 6, lane = tid & 63;
    const int ln = lane & 15, q = lane >> 4;

    floatx4 acc[4][2];
#pragma unroll
    for (int mt = 0; mt < 4; mt++)
#pragma unroll
        for (int nt = 0; nt < 2; nt++) acc[mt][nt] = (floatx4)(0.f);

    for (int c4 = 0; c4 < 2; c4++) {
        for (int i = tid; i < 1296; i += 256) {
            int p = i >> 2, g = i & 3;
            int gy = y0 + p / 18 - 1, gx = x0 + p % 18 - 1;
            uint4 v = make_uint4(0, 0, 0, 0);
            if (gy >= 0 && gy < 128 && gx >= 0 && gx < 128)
                v = *(const uint4*)&hT[(((size_t)b * 128 + gy) * 128 + gx) * 64 + c4 * 32 + g * 8];
            *(uint4*)&in_s[p * 40 + g * 8] = v;
        }
#pragma unroll
        for (int it = 0; it < 5; it++) {
            int f = it * 256 + tid;
            if (f < 1152) {
                int g = f & 3, co = (f >> 2) & 31, tap = f >> 7;
                uint4 v = *(const uint4*)&w2p[(((size_t)c4 * 9 + tap) * 32 + co) * 32 + g * 8];
                *(uint4*)&w_s[(tap * 32 + co) * 40 + g * 8] = v;
            }
        }
        __syncthreads();

#pragma unroll
        for (int tap = 0; tap < 9; tap++) {
            const int dy = tap / 3, dx = tap % 3;
            short8 a[4];
#pragma unroll
            for (int mt = 0; mt < 4; mt++)
                a[mt] = *(const short8*)&in_s[((wid * 4 + mt + dy) * 18 + ln + dx) * 40 + q * 8];
#pragma unroll
            for (int nt = 0; nt < 2; nt++) {
                short8 bf = *(const short8*)&w_s[(tap * 32 + nt * 16 + ln) * 40 + q * 8];
#pragma unroll
                for (int mt = 0; mt < 4; mt++)
                    acc[mt][nt] = __builtin_amdgcn_mfma_f32_16x16x32_bf16(a[mt], bf, acc[mt][nt], 0, 0, 0);
            }
        }
        __syncthreads();
    }

#pragma unroll
    for (int nt = 0; nt < 2; nt++) {
        int co = nt * 16 + ln;
        if (co < 18) {
            float bs = b2[co];
#pragma unroll
            for (int mt = 0; mt < 4; mt++) {
                int gy = y0 + wid * 4 + mt;
#pragma unroll
                for (int r = 0; r < 4; r++) {
                    int px = q * 4 + r;
                    cond[(((size_t)b * 128 + gy) * 128 + x0 + px) * 18 + co] = acc[mt][nt][r] + bs;
                }
            }
        }
    }
}

// ---------------------------------------------------------------------------
// apply: rolling y-strip. Thread = (x4 column, sub-row s); strip = 32 rows.
// 10 row-loads per 8 output rows (1.25x). grid (2, 16, 8); block 256.
// ---------------------------------------------------------------------------
__global__ __launch_bounds__(256) void apply_kernel(
    const float* __restrict__ img, const float* __restrict__ cond,
    float* __restrict__ out)
{
    const int tid = threadIdx.x;
    const int xl = tid & 63, s = tid >> 6;
    const int x4 = blockIdx.x * 64 + xl;
    const int base = blockIdx.y * 32;
    const int b = blockIdx.z;
    const int cyb = base >> 2;

    float4 acc[3][6];
#pragma unroll
    for (int sl = 0; sl < 3; sl++)
#pragma unroll
        for (int c = 0; c < 6; c++) acc[sl][c] = make_float4(0.f, 0.f, 0.f, 0.f);

#pragma unroll
    for (int m = 0; m <= 9; m++) {
        const int r = base + s + 4 * (m - 1);
        const bool rok = (r >= 0) && (r < 512);
        float4 v[6][3];
#pragma unroll
        for (int c = 0; c < 6; c++)
#pragma unroll
            for (int i = 0; i < 3; i++) {
                int xx = x4 * 4 + i * 4 - 4;
                v[c][i] = make_float4(0.f, 0.f, 0.f, 0.f);
                if (rok && xx >= 0 && xx < 512)
                    v[c][i] = *(const float4*)&img[(((size_t)b * 6 + c) * 512 + r) * 512 + xx];
            }
#pragma unroll
        for (int j = m - 2; j <= m; j++) {
            if (j >= 0 && j < 8) {
                const int jy = m - j;
                const int slot = j % 3;
                const float* cw = &cond[(((size_t)b * 128 + cyb + j) * 128 + x4) * 18];
#pragma unroll
                for (int g = 0; g < 2; g++)
#pragma unroll
                    for (int i = 0; i < 3; i++) {
                        float wv = cw[g * 9 + i * 3 + jy];
#pragma unroll
                        for (int cc = 0; cc < 3; cc++) {
                            int c = g * 3 + cc;
                            acc[slot][c].x += v[c][i].x * wv;
                            acc[slot][c].y += v[c][i].y * wv;
                            acc[slot][c].z += v[c][i].z * wv;
                            acc[slot][c].w += v[c][i].w * wv;
                        }
                    }
            }
        }
        const int jd = m - 2;
        if (jd >= 0 && jd < 8) {
            const int o = base + 4 * jd + s;
            const int slot = jd % 3;
#pragma unroll
            for (int c = 0; c < 6; c++) {
                *(float4*)&out[(((size_t)b * 6 + c) * 512 + o) * 512 + x4 * 4] = acc[slot][c];
                acc[slot][c] = make_float4(0.f, 0.f, 0.f, 0.f);
            }
        }
    }
}

// ---------------------------------------------------------------------------
extern "C" void kernel_launch(void* const* d_in, const int* in_sizes, int n_in,
                              void* d_out, int out_size, void* d_ws, size_t ws_size,
                              hipStream_t stream)
{
    const float* img   = (const float*)d_in[0];
    const float* ctrl  = (const float*)d_in[1];
    const float* w1    = (const float*)d_in[2];
    const float* b1    = (const float*)d_in[3];
    const float* gamma = (const float*)d_in[4];
    const float* beta  = (const float*)d_in[5];
    const float* mean  = (const float*)d_in[6];
    const float* var   = (const float*)d_in[7];
    const float* w2    = (const float*)d_in[8];
    const float* b2    = (const float*)d_in[9];
    float* out = (float*)d_out;

    char* ws = (char*)d_ws;
    unsigned short* hbuf = (unsigned short*)ws;                 // 16,777,216 B
    float*          cond = (float*)(ws + 16777216);             //  9,437,184 B
    unsigned short* w1p  = (unsigned short*)(ws + 26214400);    //    147,456 B
    unsigned short* w2p  = (unsigned short*)(ws + 26361856);    //     36,864 B

    prep_w_kernel<<<360, 256, 0, stream>>>(w1, w2, w1p, w2p);
    conv1_mfma<<<dim3(8, 8, 8), 256, 0, stream>>>(ctrl, w1p, b1, gamma, beta, mean, var, hbuf);
    conv2_mfma<<<dim3(8, 8, 8), 256, 0, stream>>>(hbuf, w2p, b2, cond);
    apply_kernel<<<dim3(2, 16, 8), 256, 0, stream>>>(img, cond, out);
}